// Round 5
// baseline (135.537 us; speedup 1.0000x reference)
//
#include <hip/hip_runtime.h>
#include <cstdint>

// MHA forward, MI355X gfx950.
// cvt+transpose(W) ; QKV GEMM (fp32 A folded-cvt reg-stage + fp16 B gld_lds,
// T3 dbuf) ; split-KV flash attention (2 splits, 4 blocks/CU, 32x32x16 MFMA,
// swapped QK^T, in-register softmax, cvt_pkrtz+permlane32_swap, defer-max,
// dbuf K/V, FSWZ LDS) ; combine ; out GEMM -> fp32.

typedef _Float16 h8 __attribute__((ext_vector_type(8)));
typedef float f4 __attribute__((ext_vector_type(4)));
typedef float f16v __attribute__((ext_vector_type(16)));
typedef unsigned int u32x4 __attribute__((ext_vector_type(4)));
typedef const unsigned int __attribute__((address_space(1)))* gp1_t;
typedef unsigned int __attribute__((address_space(3)))* lp3_t;

// row-dependent granule swizzle: spreads 128B-periodic rows across banks.
#define FSWZ(r) ((((r) ^ ((r) >> 3))) & 7)

__device__ __forceinline__ void gld_lds16(const void* g, const void* l) {
  __builtin_amdgcn_global_load_lds((gp1_t)(uintptr_t)g,
                                   (lp3_t)(unsigned int)(uintptr_t)l, 16, 0, 0);
}
__device__ __forceinline__ unsigned pkh(float a, float b) {
  return __builtin_bit_cast(unsigned, __builtin_amdgcn_cvt_pkrtz(a, b));
}
__device__ __forceinline__ void plswap(unsigned& a, unsigned& b) {
  asm volatile("v_permlane32_swap_b32 %0, %1" : "+v"(a), "+v"(b));
}

// ---------------- W convert+transpose ----------------

__global__ void cvt_w4(const float* __restrict__ wq, const float* __restrict__ wk,
                       const float* __restrict__ wv, const float* __restrict__ wo,
                       _Float16* __restrict__ WT) {
  const int z = blockIdx.z;
  const float* W = (z == 0) ? wq : (z == 1) ? wk : (z == 2) ? wv : wo;
  _Float16* o = WT + (size_t)z * 1048576;
  const int k = blockIdx.x * 256 + threadIdx.x;
  const int n0 = blockIdx.y * 4;
  float4 w = *(const float4*)(W + (size_t)k * 1024 + n0);
  o[(size_t)(n0 + 0) * 1024 + k] = (_Float16)w.x;
  o[(size_t)(n0 + 1) * 1024 + k] = (_Float16)w.y;
  o[(size_t)(n0 + 2) * 1024 + k] = (_Float16)w.z;
  o[(size_t)(n0 + 3) * 1024 + k] = (_Float16)w.w;
}

// ---------------- QKV GEMM: C = A32(4096x1024) * Bt^T + bias ----------------
// 128x128 tile, BK=64, 4 waves, T3 dbuf. A is fp32 in HBM: reg-stage
// (load float4 early -> cvt_pkrtz -> swizzled ds_write into idle buffer).
// B (fp16 weights) staged via source-swizzled gld_lds.

#define A_LOAD(KT)                                                             \
  do {                                                                         \
    _Pragma("unroll") for (int i_ = 0; i_ < 4; ++i_) {                         \
      const int idx_ = i_ * 256 + tid;                                         \
      const int r_ = idx_ >> 3, g_ = idx_ & 7;                                 \
      const float* ap_ = A32 + (size_t)(row0 + r_) * 1024 + (KT) * 64 + g_ * 8;\
      fa[i_] = *(const float4*)ap_;                                            \
      fb[i_] = *(const float4*)(ap_ + 4);                                      \
    }                                                                          \
  } while (0)

#define A_WRITE(BUF)                                                           \
  do {                                                                         \
    _Pragma("unroll") for (int i_ = 0; i_ < 4; ++i_) {                         \
      const int idx_ = i_ * 256 + tid;                                         \
      const int r_ = idx_ >> 3, g_ = idx_ & 7;                                 \
      u32x4 w_ = {pkh(fa[i_].x, fa[i_].y), pkh(fa[i_].z, fa[i_].w),            \
                  pkh(fb[i_].x, fb[i_].y), pkh(fb[i_].z, fb[i_].w)};           \
      *(u32x4*)&As[BUF][r_ * 64 + ((g_ ^ FSWZ(r_)) << 3)] = w_;                \
    }                                                                          \
  } while (0)

#define B_STAGE(BUF, KT)                                                       \
  do {                                                                         \
    _Pragma("unroll") for (int rr_ = 0; rr_ < 4; ++rr_) {                      \
      const int idx_ = rr_ * 256 + tid;                                        \
      const int r_ = idx_ >> 3, g_ = idx_ & 7;                                 \
      gld_lds16(Bt + (size_t)(col0 + r_) * 1024 + (KT) * 64 + (g_ ^ FSWZ(r_)) * 8,\
                &Bs[BUF][(rr_ * 256 + wave * 64) * 8]);                        \
    }                                                                          \
  } while (0)

__global__ __launch_bounds__(256, 2) void gemm_qkv(const float* __restrict__ Qf,
                                                   const float* __restrict__ Kf,
                                                   const float* __restrict__ Vf,
                                                   const _Float16* __restrict__ WT,
                                                   const float* __restrict__ bq,
                                                   const float* __restrict__ bk,
                                                   const float* __restrict__ bv,
                                                   _Float16* __restrict__ qkv16) {
  __shared__ _Float16 As[2][8192];
  __shared__ _Float16 Bs[2][8192];
  const int z = blockIdx.z;
  const float* A32 = (z == 0) ? Qf : (z == 1) ? Kf : Vf;
  const _Float16* Bt = WT + (size_t)z * 1048576;
  const float* bias = (z == 0) ? bq : (z == 1) ? bk : bv;
  _Float16* out16 = qkv16 + (size_t)z * 4194304;
  const int tid = threadIdx.x;
  const int wave = tid >> 6, lane = tid & 63;
  const int lg = lane >> 4, ll = lane & 15;
  const int wr = wave >> 1, wc = wave & 1;
  const int row0 = blockIdx.x * 128, col0 = blockIdx.y * 128;  // x=row: XCD reuse
  f4 acc[4][4] = {};
  float4 fa[4], fb[4];
  A_LOAD(0);
  B_STAGE(0, 0);
  A_WRITE(0);
  __syncthreads();
  int cur = 0;
  for (int kt = 0; kt < 16; ++kt) {
    const bool pre = (kt + 1 < 16);
    if (pre) { A_LOAD(kt + 1); B_STAGE(cur ^ 1, kt + 1); }
#pragma unroll
    for (int kk = 0; kk < 2; ++kk) {
      h8 af[4], bf[4];
#pragma unroll
      for (int mi = 0; mi < 4; ++mi) {
        const int r = wr * 64 + mi * 16 + ll;
        af[mi] = *(const h8*)&As[cur][r * 64 + (((kk * 4 + lg) ^ FSWZ(r)) << 3)];
      }
#pragma unroll
      for (int ni = 0; ni < 4; ++ni) {
        const int r = wc * 64 + ni * 16 + ll;
        bf[ni] = *(const h8*)&Bs[cur][r * 64 + (((kk * 4 + lg) ^ FSWZ(r)) << 3)];
      }
#pragma unroll
      for (int mi = 0; mi < 4; ++mi)
#pragma unroll
        for (int ni = 0; ni < 4; ++ni)
          acc[mi][ni] = __builtin_amdgcn_mfma_f32_16x16x32_f16(af[mi], bf[ni],
                                                               acc[mi][ni], 0, 0, 0);
    }
    if (pre) A_WRITE(cur ^ 1);  // idle buffer: no race; barrier publishes
    __syncthreads();
    cur ^= 1;
  }
#pragma unroll
  for (int ni = 0; ni < 4; ++ni) {
    const int c = col0 + wc * 64 + ni * 16 + ll;
    const float bv = bias[c];
#pragma unroll
    for (int mi = 0; mi < 4; ++mi) {
#pragma unroll
      for (int i = 0; i < 4; ++i) {
        const int r = row0 + wr * 64 + mi * 16 + lg * 4 + i;
        const float val = acc[mi][ni][i] + bv;
        // permuted store: [B=2][H=16][S=2048][Hd=64]
        const int b = r >> 11, s = r & 2047, h = c >> 6, hd = c & 63;
        out16[((size_t)((b * 16 + h) * 2048 + s)) * 64 + hd] = (_Float16)val;
      }
    }
  }
}

// ---------------- out GEMM: C = A16(4096x1024) * WoT^T + bias -> fp32 ----------------

#define G_STAGE16(BUF, KT)                                                     \
  do {                                                                         \
    _Pragma("unroll") for (int rr_ = 0; rr_ < 4; ++rr_) {                      \
      const int idx_ = rr_ * 256 + tid;                                        \
      const int r_ = idx_ >> 3, g_ = idx_ & 7;                                 \
      const int lb_ = (rr_ * 256 + wave * 64) * 8;                             \
      gld_lds16(A16 + (size_t)(row0 + r_) * 1024 + (KT) * 64 + (g_ ^ FSWZ(r_)) * 8,\
                &As[BUF][lb_]);                                                \
      gld_lds16(WoT + (size_t)(col0 + r_) * 1024 + (KT) * 64 + (g_ ^ FSWZ(r_)) * 8,\
                &Bs[BUF][lb_]);                                                \
    }                                                                          \
  } while (0)

__global__ __launch_bounds__(256, 2) void gemm_out_k(const _Float16* __restrict__ A16,
                                                     const _Float16* __restrict__ WoT,
                                                     const float* __restrict__ bo,
                                                     float* __restrict__ out) {
  __shared__ _Float16 As[2][8192];
  __shared__ _Float16 Bs[2][8192];
  const int tid = threadIdx.x;
  const int wave = tid >> 6, lane = tid & 63;
  const int lg = lane >> 4, ll = lane & 15;
  const int wr = wave >> 1, wc = wave & 1;
  const int row0 = blockIdx.x * 128, col0 = blockIdx.y * 128;
  f4 acc[4][4] = {};
  G_STAGE16(0, 0);
  __syncthreads();
  int cur = 0;
  for (int kt = 0; kt < 16; ++kt) {
    if (kt + 1 < 16) G_STAGE16(cur ^ 1, kt + 1);
#pragma unroll
    for (int kk = 0; kk < 2; ++kk) {
      h8 af[4], bf[4];
#pragma unroll
      for (int mi = 0; mi < 4; ++mi) {
        const int r = wr * 64 + mi * 16 + ll;
        af[mi] = *(const h8*)&As[cur][r * 64 + (((kk * 4 + lg) ^ FSWZ(r)) << 3)];
      }
#pragma unroll
      for (int ni = 0; ni < 4; ++ni) {
        const int r = wc * 64 + ni * 16 + ll;
        bf[ni] = *(const h8*)&Bs[cur][r * 64 + (((kk * 4 + lg) ^ FSWZ(r)) << 3)];
      }
#pragma unroll
      for (int mi = 0; mi < 4; ++mi)
#pragma unroll
        for (int ni = 0; ni < 4; ++ni)
          acc[mi][ni] = __builtin_amdgcn_mfma_f32_16x16x32_f16(af[mi], bf[ni],
                                                               acc[mi][ni], 0, 0, 0);
    }
    __syncthreads();
    cur ^= 1;
  }
#pragma unroll
  for (int ni = 0; ni < 4; ++ni) {
    const int c = col0 + wc * 64 + ni * 16 + ll;
    const float bv = bo[c];
#pragma unroll
    for (int mi = 0; mi < 4; ++mi)
#pragma unroll
      for (int i = 0; i < 4; ++i) {
        const int r = row0 + wr * 64 + mi * 16 + lg * 4 + i;
        out[(size_t)r * 1024 + c] = acc[mi][ni][i] + bv;
      }
  }
}

// ---------------- split-KV flash attention (swapped QK^T, 32x32x16) ----------------
// 1024 blocks x 256 thr (4 waves x 32 q-rows, QBLK=128), 2 KV-splits of 1024
// keys -> 4 blocks/CU. XCD-chunked heads. KVBLK=64 dbuf; FSWZ swizzle.
// Output: per-split normalized O (fp16) + per-row (m, l) for the combiner.

#define STAGE_K(BUF, KT)                                                      \
  do {                                                                        \
    _Pragma("unroll") for (int rr_ = 0; rr_ < 2; ++rr_) {                     \
      const int idx_ = rr_ * 256 + tid;                                       \
      const int r_ = idx_ >> 3, g_ = idx_ & 7;                                \
      gld_lds16(kbp + (size_t)((KT) * 64 + r_) * 64 + ((g_ ^ FSWZ(r_)) * 8),  \
                &Ks[BUF][(rr_ * 256 + wave * 64) * 8]);                       \
    }                                                                         \
  } while (0)

#define LOAD_V(KT, VA, VC)                                                    \
  do {                                                                        \
    const _Float16* vp_ = vbp + (size_t)((KT) * 64 + vkey0) * 64 + vhd0;      \
    VA = *(const uint4*)vp_;                                                  \
    VC = *(const uint4*)(vp_ + 64);                                           \
  } while (0)

#define WRITE_V(BUF, VA, VC)                                                  \
  do {                                                                        \
    const unsigned short* pa_ = (const unsigned short*)&VA;                   \
    const unsigned short* pc_ = (const unsigned short*)&VC;                   \
    _Pragma("unroll") for (int j_ = 0; j_ < 8; ++j_) {                        \
      const int row_ = vhd0 + j_;                                             \
      *(unsigned*)&Vt[BUF][row_ * 64 + (((vkey0 >> 3) ^ FSWZ(row_)) << 3) +   \
                           (vkey0 & 7)] =                                     \
          (unsigned)pa_[j_] | ((unsigned)pc_[j_] << 16);                      \
    }                                                                         \
  } while (0)

#define PV_STEP(SX, PP, KBP)                                                  \
  do {                                                                        \
    unsigned wA = pkh(SX[(PP) + 0], SX[(PP) + 1]);                            \
    unsigned wB = pkh(SX[(PP) + 2], SX[(PP) + 3]);                            \
    unsigned wC = pkh(SX[(PP) + 4], SX[(PP) + 5]);                            \
    unsigned wD = pkh(SX[(PP) + 6], SX[(PP) + 7]);                            \
    plswap(wA, wC);                                                           \
    plswap(wB, wD);                                                           \
    u32x4 afu = {wA, wB, wC, wD};                                             \
    h8 af = __builtin_bit_cast(h8, afu);                                      \
    const int c_ = (KBP) * 2 + hi;                                            \
    h8 vf0 = *(const h8*)&Vt[cur][l31 * 64 + ((c_ ^ FSWZ(l31)) << 3)];        \
    h8 vf1 = *(const h8*)&Vt[cur][(32 + l31) * 64 +                           \
                                  ((c_ ^ FSWZ(32 + l31)) << 3)];              \
    acc0 = __builtin_amdgcn_mfma_f32_32x32x16_f16(af, vf0, acc0, 0, 0, 0);    \
    acc1 = __builtin_amdgcn_mfma_f32_32x32x16_f16(af, vf1, acc1, 0, 0, 0);    \
  } while (0)

__global__ __launch_bounds__(256, 4) void attn_kernel(
    const _Float16* __restrict__ q16, const _Float16* __restrict__ k16,
    const _Float16* __restrict__ v16, _Float16* __restrict__ Op,
    float2* __restrict__ mlp) {
  __shared__ _Float16 Ks[2][4096];  // [64 keys][64 hd], FSWZ-swizzled granules
  __shared__ _Float16 Vt[2][4096];  // [64 hd][64 keys], FSWZ-swizzled
  __shared__ float Fb[4][32];       // per-wave inv broadcast
  const int tid = threadIdx.x;
  const int wave = tid >> 6, lane = tid & 63;
  const int l31 = lane & 31, hi = lane >> 5;
  // XCD-chunked: xcd = blk&7 owns heads [xcd*4, xcd*4+4); 2 splits x 16 qb
  const int blk = blockIdx.x;
  const int xcd = blk & 7, j = blk >> 3;   // j in 0..127
  const int bh = xcd * 4 + (j >> 5);
  const int split = (j >> 4) & 1;
  const int qb = j & 15;
  const int q0w = qb * 128 + wave * 32;
  const _Float16* qbp = q16 + (size_t)bh * 131072;
  const _Float16* kbp = k16 + (size_t)bh * 131072 + (size_t)split * 65536;
  const _Float16* vbp = v16 + (size_t)bh * 131072 + (size_t)split * 65536;
  const int vkey0 = (tid & 31) * 2, vhd0 = (tid >> 5) * 8;

  // Q fragments (B-operand): lane&31 = q col, k = hi*8+j within K=16 slice
  h8 qf0 = *(const h8*)(qbp + (size_t)(q0w + l31) * 64 + 0 + hi * 8);
  h8 qf1 = *(const h8*)(qbp + (size_t)(q0w + l31) * 64 + 16 + hi * 8);
  h8 qf2 = *(const h8*)(qbp + (size_t)(q0w + l31) * 64 + 32 + hi * 8);
  h8 qf3 = *(const h8*)(qbp + (size_t)(q0w + l31) * 64 + 48 + hi * 8);

  f16v acc0 = {}, acc1 = {};
  float mval = -1e30f, lsum = 0.f;
  const float C = 0.125f * 1.44269504089f;  // SCALE * log2(e)

  uint4 va, vc;
  STAGE_K(0, 0);
  LOAD_V(0, va, vc);
  WRITE_V(0, va, vc);
  __syncthreads();

  int cur = 0;
  for (int kt = 0; kt < 16; ++kt) {
    const bool pre = (kt + 1 < 16);
    if (pre) { STAGE_K(cur ^ 1, kt + 1); LOAD_V(kt + 1, va, vc); }

    // ---- QK^T: S^T[key][q] ----
    f16v s0 = {}, s1 = {};
    __builtin_amdgcn_s_setprio(1);
#pragma unroll
    for (int kc = 0; kc < 4; ++kc) {
      const int c = kc * 2 + hi;
      h8 k0 = *(const h8*)&Ks[cur][l31 * 64 + ((c ^ FSWZ(l31)) << 3)];
      h8 k1 = *(const h8*)&Ks[cur][(32 + l31) * 64 + ((c ^ FSWZ(32 + l31)) << 3)];
      h8 qf = (kc == 0) ? qf0 : (kc == 1) ? qf1 : (kc == 2) ? qf2 : qf3;
      s0 = __builtin_amdgcn_mfma_f32_32x32x16_f16(k0, qf, s0, 0, 0, 0);
      s1 = __builtin_amdgcn_mfma_f32_32x32x16_f16(k1, qf, s1, 0, 0, 0);
    }
    __builtin_amdgcn_s_setprio(0);

    // ---- tile max (in-register tree + one cross-half shuffle) ----
    float t[8];
#pragma unroll
    for (int j2 = 0; j2 < 8; ++j2)
      t[j2] = fmaxf(fmaxf(s0[j2], s0[j2 + 8]), fmaxf(s1[j2], s1[j2 + 8]));
    float pm = fmaxf(fmaxf(fmaxf(t[0], t[1]), fmaxf(t[2], t[3])),
                     fmaxf(fmaxf(t[4], t[5]), fmaxf(t[6], t[7])));
    pm = fmaxf(pm, __shfl_xor(pm, 32));
    const float pms = pm * C;

    // ---- defer-max rescale (rare) ----
    if (__any(pms > mval + 8.0f)) {
      const float mnew = fmaxf(mval, pms);
      const float f = __builtin_amdgcn_exp2f(mval - mnew);
      mval = mnew;
      lsum *= f;
      Fb[wave][l31] = f;
      const f4 fr0 = *(const f4*)&Fb[wave][0 + 4 * hi];
      const f4 fr1 = *(const f4*)&Fb[wave][8 + 4 * hi];
      const f4 fr2 = *(const f4*)&Fb[wave][16 + 4 * hi];
      const f4 fr3 = *(const f4*)&Fb[wave][24 + 4 * hi];
#pragma unroll
      for (int r = 0; r < 16; ++r) {
        const float fx = (r < 4 ? fr0 : r < 8 ? fr1 : r < 12 ? fr2 : fr3)[r & 3];
        acc0[r] *= fx;
        acc1[r] *= fx;
      }
    }

    // ---- P = exp2(s*C - m); per-lane partial sum ----
#pragma unroll
    for (int r = 0; r < 16; ++r) {
      s0[r] = __builtin_amdgcn_exp2f(s0[r] * C - mval);
      s1[r] = __builtin_amdgcn_exp2f(s1[r] * C - mval);
    }
    float z[8];
#pragma unroll
    for (int j2 = 0; j2 < 8; ++j2)
      z[j2] = (s0[j2] + s0[j2 + 8]) + (s1[j2] + s1[j2 + 8]);
    lsum += ((z[0] + z[1]) + (z[2] + z[3])) + ((z[4] + z[5]) + (z[6] + z[7]));

    // ---- PV: acc += P * V ----
    __builtin_amdgcn_s_setprio(1);
    PV_STEP(s0, 0, 0);
    PV_STEP(s0, 8, 1);
    PV_STEP(s1, 0, 2);
    PV_STEP(s1, 8, 3);
    __builtin_amdgcn_s_setprio(0);

    if (pre) WRITE_V(cur ^ 1, va, vc);
    __syncthreads();
    cur ^= 1;
  }

  // ---- epilogue: normalized partial O + (m, l) ----
  lsum += __shfl_xor(lsum, 32);
  if (!hi) mlp[split * 65536 + bh * 2048 + q0w + l31] = make_float2(mval, lsum);
  const float inv = 1.0f / lsum;
  Fb[wave][l31] = inv;
  const f4 ir0 = *(const f4*)&Fb[wave][0 + 4 * hi];
  const f4 ir1 = *(const f4*)&Fb[wave][8 + 4 * hi];
  const f4 ir2 = *(const f4*)&Fb[wave][16 + 4 * hi];
  const f4 ir3 = *(const f4*)&Fb[wave][24 + 4 * hi];
#pragma unroll
  for (int r = 0; r < 16; ++r) {
    const float fx = (r < 4 ? ir0 : r < 8 ? ir1 : r < 12 ? ir2 : ir3)[r & 3];
    const int srow = q0w + (r & 3) + 8 * (r >> 2) + 4 * hi;
    _Float16* op = Op + (size_t)split * 4194304 +
                   ((size_t)(bh * 2048 + srow)) * 64 + l31;
    op[0] = (_Float16)(acc0[r] * fx);
    op[32] = (_Float16)(acc1[r] * fx);
  }
}

// ---------------- split combine: aout = (w0*O0 + w1*O1)/(w0+w1) ----------------

__global__ __launch_bounds__(256) void cmb(const _Float16* __restrict__ Op,
                                           const float2* __restrict__ mlp,
                                           _Float16* __restrict__ ao) {
  const int gid = blockIdx.x * 256 + threadIdx.x;  // 524288 total
  const int R = gid >> 3, o = gid & 7;
  const float2 a = mlp[R];
  const float2 c = mlp[65536 + R];
  const float M = fmaxf(a.x, c.x);
  float w0 = __builtin_amdgcn_exp2f(a.x - M) * a.y;
  float w1 = __builtin_amdgcn_exp2f(c.x - M) * c.y;
  const float inv = 1.0f / (w0 + w1);
  w0 *= inv;
  w1 *= inv;
  h8 p0 = *(const h8*)(Op + (size_t)R * 64 + o * 8);
  h8 p1 = *(const h8*)(Op + 4194304 + (size_t)R * 64 + o * 8);
  const int bh = R >> 11, s = R & 2047, b = bh >> 4, h = bh & 15;
  h8 r;
#pragma unroll
  for (int j = 0; j < 8; ++j)
    r[j] = (_Float16)(w0 * (float)p0[j] + w1 * (float)p1[j]);
  *(h8*)(ao + ((size_t)(b * 2048 + s)) * 1024 + h * 64 + o * 8) = r;
}

// ---------------- launch ----------------

extern "C" void kernel_launch(void* const* d_in, const int* in_sizes, int n_in,
                              void* d_out, int out_size, void* d_ws, size_t ws_size,
                              hipStream_t stream) {
  const float* Q  = (const float*)d_in[0];
  const float* K  = (const float*)d_in[1];
  const float* V  = (const float*)d_in[2];
  const float* Wq = (const float*)d_in[3];
  const float* bq = (const float*)d_in[4];
  const float* Wk = (const float*)d_in[5];
  const float* bk = (const float*)d_in[6];
  const float* Wv = (const float*)d_in[7];
  const float* bv = (const float*)d_in[8];
  const float* Wo = (const float*)d_in[9];
  const float* bo = (const float*)d_in[10];

  _Float16* H      = (_Float16*)d_ws;
  _Float16* Op     = H;                         // 2 x 4194304 (split partial O)
  float2*   mlp    = (float2*)(H + 8388608);    // 2 x 65536 float2 (m, l)
  _Float16* WT     = H + 12582912;              // 4 x 1048576 (W^T fp16)
  _Float16* qkv16  = H + 16777216;              // 3 x 4194304 ([B,H,S,Hd] q,k,v)
  _Float16* aout16 = H + 29360128;              // 4194304 ([B,S,D] attention out)
  float* out = (float*)d_out;

  cvt_w4<<<dim3(4, 256, 4), 256, 0, stream>>>(Wq, Wk, Wv, Wo, WT);
  gemm_qkv<<<dim3(32, 8, 3), 256, 0, stream>>>(Q, K, V, WT, bq, bk, bv, qkv16);
  attn_kernel<<<dim3(1024), 256, 0, stream>>>(qkv16, qkv16 + 4194304,
                                              qkv16 + 8388608, Op, mlp);
  cmb<<<dim3(2048), 256, 0, stream>>>(Op, mlp, aout16);
  gemm_out_k<<<dim3(32, 8), 256, 0, stream>>>(aout16, WT + 3145728, bo, out);
}

// Round 6
// 124.986 us; speedup vs baseline: 1.0844x; 1.0844x over previous
//
#include <hip/hip_runtime.h>
#include <cstdint>

// MHA forward, MI355X gfx950.
// cvt+transpose(W) ; QKV GEMM (fp32 A folded-cvt reg-stage, T3 dbuf, Q
// pre-scaled by SCALE*log2e) ; flash attention (two-tile software pipeline:
// QK(t+1) || PV(t) MFMA, softmax(t+1) VALU overlaps PV latency; swapped QK^T,
// in-register softmax, cvt_pkrtz+permlane32_swap, defer-max, dbuf K/V, FSWZ) ;
// out GEMM (128x64 tiles, 512 blocks) -> fp32.

typedef _Float16 h8 __attribute__((ext_vector_type(8)));
typedef float f4 __attribute__((ext_vector_type(4)));
typedef float f16v __attribute__((ext_vector_type(16)));
typedef unsigned int u32x4 __attribute__((ext_vector_type(4)));
typedef const unsigned int __attribute__((address_space(1)))* gp1_t;
typedef unsigned int __attribute__((address_space(3)))* lp3_t;

// row-dependent granule swizzle: spreads 128B-periodic rows across banks.
#define FSWZ(r) ((((r) ^ ((r) >> 3))) & 7)

__device__ __forceinline__ void gld_lds16(const void* g, const void* l) {
  __builtin_amdgcn_global_load_lds((gp1_t)(uintptr_t)g,
                                   (lp3_t)(unsigned int)(uintptr_t)l, 16, 0, 0);
}
__device__ __forceinline__ unsigned pkh(float a, float b) {
  return __builtin_bit_cast(unsigned, __builtin_amdgcn_cvt_pkrtz(a, b));
}
__device__ __forceinline__ void plswap(unsigned& a, unsigned& b) {
  asm volatile("v_permlane32_swap_b32 %0, %1" : "+v"(a), "+v"(b));
}

// ---------------- W convert+transpose ----------------

__global__ void cvt_w4(const float* __restrict__ wq, const float* __restrict__ wk,
                       const float* __restrict__ wv, const float* __restrict__ wo,
                       _Float16* __restrict__ WT) {
  const int z = blockIdx.z;
  const float* W = (z == 0) ? wq : (z == 1) ? wk : (z == 2) ? wv : wo;
  _Float16* o = WT + (size_t)z * 1048576;
  const int k = blockIdx.x * 256 + threadIdx.x;
  const int n0 = blockIdx.y * 4;
  float4 w = *(const float4*)(W + (size_t)k * 1024 + n0);
  o[(size_t)(n0 + 0) * 1024 + k] = (_Float16)w.x;
  o[(size_t)(n0 + 1) * 1024 + k] = (_Float16)w.y;
  o[(size_t)(n0 + 2) * 1024 + k] = (_Float16)w.z;
  o[(size_t)(n0 + 3) * 1024 + k] = (_Float16)w.w;
}

// ---------------- QKV GEMM: C = A32(4096x1024) * Bt^T + bias ----------------
// 128x128 tile, BK=64, 4 waves, T3 dbuf. fp32 A reg-staged (float4 -> cvt_pkrtz
// -> swizzled ds_write into idle buffer); fp16 B via source-swizzled gld_lds.
// z==0 (Q): output scaled by SCALE*log2e so attn softmax is exp2(s-m).

#define A_LOAD(KT)                                                             \
  do {                                                                         \
    _Pragma("unroll") for (int i_ = 0; i_ < 4; ++i_) {                         \
      const int idx_ = i_ * 256 + tid;                                         \
      const int r_ = idx_ >> 3, g_ = idx_ & 7;                                 \
      const float* ap_ = A32 + (size_t)(row0 + r_) * 1024 + (KT) * 64 + g_ * 8;\
      fa[i_] = *(const float4*)ap_;                                            \
      fb[i_] = *(const float4*)(ap_ + 4);                                      \
    }                                                                          \
  } while (0)

#define A_WRITE(BUF)                                                           \
  do {                                                                         \
    _Pragma("unroll") for (int i_ = 0; i_ < 4; ++i_) {                         \
      const int idx_ = i_ * 256 + tid;                                         \
      const int r_ = idx_ >> 3, g_ = idx_ & 7;                                 \
      u32x4 w_ = {pkh(fa[i_].x, fa[i_].y), pkh(fa[i_].z, fa[i_].w),            \
                  pkh(fb[i_].x, fb[i_].y), pkh(fb[i_].z, fb[i_].w)};           \
      *(u32x4*)&As[BUF][r_ * 64 + ((g_ ^ FSWZ(r_)) << 3)] = w_;                \
    }                                                                          \
  } while (0)

#define B_STAGE(BUF, KT)                                                       \
  do {                                                                         \
    _Pragma("unroll") for (int rr_ = 0; rr_ < 4; ++rr_) {                      \
      const int idx_ = rr_ * 256 + tid;                                        \
      const int r_ = idx_ >> 3, g_ = idx_ & 7;                                 \
      gld_lds16(Bt + (size_t)(col0 + r_) * 1024 + (KT) * 64 + (g_ ^ FSWZ(r_)) * 8,\
                &Bs[BUF][(rr_ * 256 + wave * 64) * 8]);                        \
    }                                                                          \
  } while (0)

__global__ __launch_bounds__(256, 2) void gemm_qkv(const float* __restrict__ Qf,
                                                   const float* __restrict__ Kf,
                                                   const float* __restrict__ Vf,
                                                   const _Float16* __restrict__ WT,
                                                   const float* __restrict__ bq,
                                                   const float* __restrict__ bk,
                                                   const float* __restrict__ bv,
                                                   _Float16* __restrict__ qkv16) {
  __shared__ _Float16 As[2][8192];
  __shared__ _Float16 Bs[2][8192];
  const int z = blockIdx.z;
  const float* A32 = (z == 0) ? Qf : (z == 1) ? Kf : Vf;
  const _Float16* Bt = WT + (size_t)z * 1048576;
  const float* bias = (z == 0) ? bq : (z == 1) ? bk : bv;
  _Float16* out16 = qkv16 + (size_t)z * 4194304;
  const float scl = (z == 0) ? 0.18033688f : 1.0f;  // SCALE*log2e folded into Q
  const int tid = threadIdx.x;
  const int wave = tid >> 6, lane = tid & 63;
  const int lg = lane >> 4, ll = lane & 15;
  const int wr = wave >> 1, wc = wave & 1;
  const int row0 = blockIdx.x * 128, col0 = blockIdx.y * 128;  // x=row: XCD reuse
  f4 acc[4][4] = {};
  float4 fa[4], fb[4];
  A_LOAD(0);
  B_STAGE(0, 0);
  A_WRITE(0);
  __syncthreads();
  int cur = 0;
  for (int kt = 0; kt < 16; ++kt) {
    const bool pre = (kt + 1 < 16);
    if (pre) { A_LOAD(kt + 1); B_STAGE(cur ^ 1, kt + 1); }
#pragma unroll
    for (int kk = 0; kk < 2; ++kk) {
      h8 af[4], bf[4];
#pragma unroll
      for (int mi = 0; mi < 4; ++mi) {
        const int r = wr * 64 + mi * 16 + ll;
        af[mi] = *(const h8*)&As[cur][r * 64 + (((kk * 4 + lg) ^ FSWZ(r)) << 3)];
      }
#pragma unroll
      for (int ni = 0; ni < 4; ++ni) {
        const int r = wc * 64 + ni * 16 + ll;
        bf[ni] = *(const h8*)&Bs[cur][r * 64 + (((kk * 4 + lg) ^ FSWZ(r)) << 3)];
      }
#pragma unroll
      for (int mi = 0; mi < 4; ++mi)
#pragma unroll
        for (int ni = 0; ni < 4; ++ni)
          acc[mi][ni] = __builtin_amdgcn_mfma_f32_16x16x32_f16(af[mi], bf[ni],
                                                               acc[mi][ni], 0, 0, 0);
    }
    if (pre) A_WRITE(cur ^ 1);  // idle buffer; barrier publishes
    __syncthreads();
    cur ^= 1;
  }
#pragma unroll
  for (int ni = 0; ni < 4; ++ni) {
    const int c = col0 + wc * 64 + ni * 16 + ll;
    const float bv = bias[c];
#pragma unroll
    for (int mi = 0; mi < 4; ++mi) {
#pragma unroll
      for (int i = 0; i < 4; ++i) {
        const int r = row0 + wr * 64 + mi * 16 + lg * 4 + i;
        const float val = (acc[mi][ni][i] + bv) * scl;
        // permuted store: [B=2][H=16][S=2048][Hd=64]
        const int b = r >> 11, s = r & 2047, h = c >> 6, hd = c & 63;
        out16[((size_t)((b * 16 + h) * 2048 + s)) * 64 + hd] = (_Float16)val;
      }
    }
  }
}

// ---------------- out GEMM: C = A16(4096x1024) * WoT^T + bias -> fp32 ----------------
// 128x64 tile -> 512 blocks (2/CU). 4 waves, wave tile 64x32.

#define GO_STAGE(BUF, KT)                                                      \
  do {                                                                         \
    _Pragma("unroll") for (int rr_ = 0; rr_ < 4; ++rr_) {                      \
      const int idx_ = rr_ * 256 + tid;                                        \
      const int r_ = idx_ >> 3, g_ = idx_ & 7;                                 \
      gld_lds16(A16 + (size_t)(row0 + r_) * 1024 + (KT) * 64 + (g_ ^ FSWZ(r_)) * 8,\
                &As[BUF][(rr_ * 256 + wave * 64) * 8]);                        \
    }                                                                          \
    _Pragma("unroll") for (int rr_ = 0; rr_ < 2; ++rr_) {                      \
      const int idx_ = rr_ * 256 + tid;                                        \
      const int r_ = idx_ >> 3, g_ = idx_ & 7;                                 \
      gld_lds16(WoT + (size_t)(col0 + r_) * 1024 + (KT) * 64 + (g_ ^ FSWZ(r_)) * 8,\
                &Bs[BUF][(rr_ * 256 + wave * 64) * 8]);                        \
    }                                                                          \
  } while (0)

__global__ __launch_bounds__(256, 2) void gemm_out_k(const _Float16* __restrict__ A16,
                                                     const _Float16* __restrict__ WoT,
                                                     const float* __restrict__ bo,
                                                     float* __restrict__ out) {
  __shared__ _Float16 As[2][8192];
  __shared__ _Float16 Bs[2][4096];
  const int tid = threadIdx.x;
  const int wave = tid >> 6, lane = tid & 63;
  const int lg = lane >> 4, ll = lane & 15;
  const int wr = wave >> 1, wc = wave & 1;
  const int row0 = blockIdx.x * 128, col0 = blockIdx.y * 64;
  f4 acc[4][2] = {};
  GO_STAGE(0, 0);
  __syncthreads();
  int cur = 0;
  for (int kt = 0; kt < 16; ++kt) {
    if (kt + 1 < 16) GO_STAGE(cur ^ 1, kt + 1);
#pragma unroll
    for (int kk = 0; kk < 2; ++kk) {
      h8 af[4], bf[2];
#pragma unroll
      for (int mi = 0; mi < 4; ++mi) {
        const int r = wr * 64 + mi * 16 + ll;
        af[mi] = *(const h8*)&As[cur][r * 64 + (((kk * 4 + lg) ^ FSWZ(r)) << 3)];
      }
#pragma unroll
      for (int ni = 0; ni < 2; ++ni) {
        const int r = wc * 32 + ni * 16 + ll;
        bf[ni] = *(const h8*)&Bs[cur][r * 64 + (((kk * 4 + lg) ^ FSWZ(r)) << 3)];
      }
#pragma unroll
      for (int mi = 0; mi < 4; ++mi)
#pragma unroll
        for (int ni = 0; ni < 2; ++ni)
          acc[mi][ni] = __builtin_amdgcn_mfma_f32_16x16x32_f16(af[mi], bf[ni],
                                                               acc[mi][ni], 0, 0, 0);
    }
    __syncthreads();
    cur ^= 1;
  }
#pragma unroll
  for (int ni = 0; ni < 2; ++ni) {
    const int c = col0 + wc * 32 + ni * 16 + ll;
    const float bv = bo[c];
#pragma unroll
    for (int mi = 0; mi < 4; ++mi)
#pragma unroll
      for (int i = 0; i < 4; ++i) {
        const int r = row0 + wr * 64 + mi * 16 + lg * 4 + i;
        out[(size_t)r * 1024 + c] = acc[mi][ni][i] + bv;
      }
  }
}

// ---------------- flash attention: two-tile software pipeline ----------------
// 512 blocks x 256 thr (4 waves x 32 q-rows). Per iter t:
//   LOAD_V(t+2) issue ; QK(t+1) MFMA ; PV(t) MFMA ; barrier ;
//   STAGE_K(t+2)+WRITE_V(t+2) ; softmax+pack(t+1) VALU (overlaps PV latency) ;
//   barrier. Q pre-scaled: softmax is exp2(s - m).

#define STAGE_K(BUF, KT)                                                      \
  do {                                                                        \
    _Pragma("unroll") for (int rr_ = 0; rr_ < 2; ++rr_) {                     \
      const int idx_ = rr_ * 256 + tid;                                       \
      const int r_ = idx_ >> 3, g_ = idx_ & 7;                                \
      gld_lds16(kbp + (size_t)((KT) * 64 + r_) * 64 + ((g_ ^ FSWZ(r_)) * 8),  \
                &Ks[BUF][(rr_ * 256 + wave * 64) * 8]);                       \
    }                                                                         \
  } while (0)

#define LOAD_V(KT)                                                            \
  do {                                                                        \
    const _Float16* vp_ = vbp + (size_t)((KT) * 64 + vkey0) * 64 + vhd0;      \
    va = *(const uint4*)vp_;                                                  \
    vc = *(const uint4*)(vp_ + 64);                                           \
  } while (0)

#define WRITE_V(BUF)                                                          \
  do {                                                                        \
    const unsigned short* pa_ = (const unsigned short*)&va;                   \
    const unsigned short* pc_ = (const unsigned short*)&vc;                   \
    _Pragma("unroll") for (int j_ = 0; j_ < 8; ++j_) {                        \
      const int row_ = vhd0 + j_;                                             \
      *(unsigned*)&Vt[BUF][row_ * 64 + (((vkey0 >> 3) ^ FSWZ(row_)) << 3) +   \
                           (vkey0 & 7)] =                                     \
          (unsigned)pa_[j_] | ((unsigned)pc_[j_] << 16);                      \
    }                                                                         \
  } while (0)

#define QK_COMPUTE(BUF, S0, S1)                                               \
  do {                                                                        \
    S0 = (f16v){};                                                            \
    S1 = (f16v){};                                                            \
    _Pragma("unroll") for (int kc_ = 0; kc_ < 4; ++kc_) {                     \
      const int c_ = kc_ * 2 + hi;                                            \
      h8 k0_ = *(const h8*)&Ks[BUF][l31 * 64 + ((c_ ^ FSWZ(l31)) << 3)];      \
      h8 k1_ = *(const h8*)&Ks[BUF][(32 + l31) * 64 +                         \
                                    ((c_ ^ FSWZ(32 + l31)) << 3)];            \
      h8 qf_ = (kc_ == 0) ? qf0 : (kc_ == 1) ? qf1 : (kc_ == 2) ? qf2 : qf3;  \
      S0 = __builtin_amdgcn_mfma_f32_32x32x16_f16(k0_, qf_, S0, 0, 0, 0);     \
      S1 = __builtin_amdgcn_mfma_f32_32x32x16_f16(k1_, qf_, S1, 0, 0, 0);     \
    }                                                                         \
  } while (0)

#define PACK_AF(DST, SX, PP)                                                  \
  do {                                                                        \
    unsigned wA = pkh(SX[(PP) + 0], SX[(PP) + 1]);                            \
    unsigned wB = pkh(SX[(PP) + 2], SX[(PP) + 3]);                            \
    unsigned wC = pkh(SX[(PP) + 4], SX[(PP) + 5]);                            \
    unsigned wD = pkh(SX[(PP) + 6], SX[(PP) + 7]);                            \
    plswap(wA, wC);                                                           \
    plswap(wB, wD);                                                           \
    DST = (u32x4){wA, wB, wC, wD};                                            \
  } while (0)

// softmax(S0,S1 in log2 domain) -> P; pack into afr[0..3]; update mval/lsum
#define SM_PK(S0, S1)                                                         \
  do {                                                                        \
    float t_[8];                                                              \
    _Pragma("unroll") for (int j2_ = 0; j2_ < 8; ++j2_)                       \
        t_[j2_] = fmaxf(fmaxf(S0[j2_], S0[j2_ + 8]),                          \
                        fmaxf(S1[j2_], S1[j2_ + 8]));                         \
    float pm_ = fmaxf(fmaxf(fmaxf(t_[0], t_[1]), fmaxf(t_[2], t_[3])),        \
                      fmaxf(fmaxf(t_[4], t_[5]), fmaxf(t_[6], t_[7])));       \
    pm_ = fmaxf(pm_, __shfl_xor(pm_, 32));                                    \
    if (__any(pm_ > mval + 8.0f)) {                                           \
      const float mn_ = fmaxf(mval, pm_);                                     \
      const float f_ = __builtin_amdgcn_exp2f(mval - mn_);                    \
      mval = mn_;                                                             \
      lsum *= f_;                                                             \
      Fb[wave][l31] = f_;                                                     \
      const f4 fr0_ = *(const f4*)&Fb[wave][0 + 4 * hi];                      \
      const f4 fr1_ = *(const f4*)&Fb[wave][8 + 4 * hi];                      \
      const f4 fr2_ = *(const f4*)&Fb[wave][16 + 4 * hi];                     \
      const f4 fr3_ = *(const f4*)&Fb[wave][24 + 4 * hi];                     \
      _Pragma("unroll") for (int r_ = 0; r_ < 16; ++r_) {                     \
        const float fx_ =                                                     \
            (r_ < 4 ? fr0_ : r_ < 8 ? fr1_ : r_ < 12 ? fr2_ : fr3_)[r_ & 3];  \
        acc0[r_] *= fx_;                                                      \
        acc1[r_] *= fx_;                                                      \
      }                                                                       \
    }                                                                         \
    _Pragma("unroll") for (int r_ = 0; r_ < 16; ++r_) {                       \
      S0[r_] = __builtin_amdgcn_exp2f(S0[r_] - mval);                         \
      S1[r_] = __builtin_amdgcn_exp2f(S1[r_] - mval);                         \
    }                                                                         \
    float z_[8];                                                              \
    _Pragma("unroll") for (int j2_ = 0; j2_ < 8; ++j2_)                       \
        z_[j2_] = (S0[j2_] + S0[j2_ + 8]) + (S1[j2_] + S1[j2_ + 8]);          \
    lsum += ((z_[0] + z_[1]) + (z_[2] + z_[3])) +                             \
            ((z_[4] + z_[5]) + (z_[6] + z_[7]));                              \
    PACK_AF(afr[0], S0, 0);                                                   \
    PACK_AF(afr[1], S0, 8);                                                   \
    PACK_AF(afr[2], S1, 0);                                                   \
    PACK_AF(afr[3], S1, 8);                                                   \
  } while (0)

#define PV_APPLY(BUF)                                                         \
  do {                                                                        \
    _Pragma("unroll") for (int i_ = 0; i_ < 4; ++i_) {                        \
      const int c_ = i_ * 2 + hi;                                             \
      h8 vf0_ = *(const h8*)&Vt[BUF][l31 * 64 + ((c_ ^ FSWZ(l31)) << 3)];     \
      h8 vf1_ = *(const h8*)&Vt[BUF][(32 + l31) * 64 +                        \
                                     ((c_ ^ FSWZ(32 + l31)) << 3)];           \
      h8 af_ = __builtin_bit_cast(h8, afr[i_]);                               \
      acc0 = __builtin_amdgcn_mfma_f32_32x32x16_f16(af_, vf0_, acc0, 0, 0, 0);\
      acc1 = __builtin_amdgcn_mfma_f32_32x32x16_f16(af_, vf1_, acc1, 0, 0, 0);\
    }                                                                         \
  } while (0)

__global__ __launch_bounds__(256, 2) void attn_kernel(
    const _Float16* __restrict__ q16, const _Float16* __restrict__ k16,
    const _Float16* __restrict__ v16, _Float16* __restrict__ aout) {
  __shared__ _Float16 Ks[2][4096];  // [64 keys][64 hd], FSWZ-swizzled granules
  __shared__ _Float16 Vt[2][4096];  // [64 hd][64 keys], FSWZ-swizzled
  __shared__ float Fb[4][32];       // per-wave rescale/inv broadcast
  const int tid = threadIdx.x;
  const int wave = tid >> 6, lane = tid & 63;
  const int l31 = lane & 31, hi = lane >> 5;
  // XCD-chunked: xcd = blk&7 owns heads [xcd*4, xcd*4+4)
  const int blk = blockIdx.x;
  const int xcd = blk & 7, j = blk >> 3;   // j in 0..63
  const int bh = xcd * 4 + (j >> 4);
  const int qb = j & 15;
  const int q0w = qb * 128 + wave * 32;
  const _Float16* qbp = q16 + (size_t)bh * 131072;
  const _Float16* kbp = k16 + (size_t)bh * 131072;
  const _Float16* vbp = v16 + (size_t)bh * 131072;
  const int vkey0 = (tid & 31) * 2, vhd0 = (tid >> 5) * 8;

  // Q fragments (B-operand), pre-scaled by SCALE*log2e at the GEMM
  h8 qf0 = *(const h8*)(qbp + (size_t)(q0w + l31) * 64 + 0 + hi * 8);
  h8 qf1 = *(const h8*)(qbp + (size_t)(q0w + l31) * 64 + 16 + hi * 8);
  h8 qf2 = *(const h8*)(qbp + (size_t)(q0w + l31) * 64 + 32 + hi * 8);
  h8 qf3 = *(const h8*)(qbp + (size_t)(q0w + l31) * 64 + 48 + hi * 8);

  f16v acc0 = {}, acc1 = {};
  f16v sr0 = {}, sr1 = {};
  u32x4 afr[4];
  float mval = -1e30f, lsum = 0.f;
  uint4 va, vc;

  // ---- prologue: stage tile0; QK(0); stage tile1; SM+PK(0) ----
  STAGE_K(0, 0);
  LOAD_V(0);
  WRITE_V(0);
  __syncthreads();                // tile0 visible
  QK_COMPUTE(0, sr0, sr1);
  STAGE_K(1, 1);
  LOAD_V(1);
  WRITE_V(1);
  SM_PK(sr0, sr1);                // af(0) ready
  __syncthreads();                // tile1 visible

  // ---- main loop: t = 0..30 ----
  for (int t = 0; t < 31; ++t) {
    const int A = t & 1, B = A ^ 1;
    if (t + 2 < 32) LOAD_V(t + 2);
    __builtin_amdgcn_s_setprio(1);
    QK_COMPUTE(B, sr0, sr1);      // QK(t+1)
    PV_APPLY(A);                  // PV(t) with af(t)
    __builtin_amdgcn_s_setprio(0);
    __builtin_amdgcn_sched_barrier(0);
    __syncthreads();              // all reads of buffer A complete
    if (t + 2 < 32) { STAGE_K(A, t + 2); WRITE_V(A); }
    SM_PK(sr0, sr1);              // softmax+pack(t+1), overlaps PV latency
    __syncthreads();              // publish tile t+2
  }
  PV_APPLY(1);                    // PV(31): tile31 lives in buffer 1

  // ---- epilogue: acc / lsum -> aout [B][S][H*Hd] fp16 ----
  lsum += __shfl_xor(lsum, 32);
  const float inv = 1.0f / lsum;
  Fb[wave][l31] = inv;
  const f4 ir0 = *(const f4*)&Fb[wave][0 + 4 * hi];
  const f4 ir1 = *(const f4*)&Fb[wave][8 + 4 * hi];
  const f4 ir2 = *(const f4*)&Fb[wave][16 + 4 * hi];
  const f4 ir3 = *(const f4*)&Fb[wave][24 + 4 * hi];
  const int b = bh >> 4, h = bh & 15;
#pragma unroll
  for (int r = 0; r < 16; ++r) {
    const float fx = (r < 4 ? ir0 : r < 8 ? ir1 : r < 12 ? ir2 : ir3)[r & 3];
    const int srow = q0w + (r & 3) + 8 * (r >> 2) + 4 * hi;
    _Float16* op = aout + ((size_t)(b * 2048 + srow)) * 1024 + h * 64 + l31;
    op[0] = (_Float16)(acc0[r] * fx);
    op[32] = (_Float16)(acc1[r] * fx);
  }
}

// ---------------- launch ----------------

extern "C" void kernel_launch(void* const* d_in, const int* in_sizes, int n_in,
                              void* d_out, int out_size, void* d_ws, size_t ws_size,
                              hipStream_t stream) {
  const float* Q  = (const float*)d_in[0];
  const float* K  = (const float*)d_in[1];
  const float* V  = (const float*)d_in[2];
  const float* Wq = (const float*)d_in[3];
  const float* bq = (const float*)d_in[4];
  const float* Wk = (const float*)d_in[5];
  const float* bk = (const float*)d_in[6];
  const float* Wv = (const float*)d_in[7];
  const float* bv = (const float*)d_in[8];
  const float* Wo = (const float*)d_in[9];
  const float* bo = (const float*)d_in[10];

  _Float16* H      = (_Float16*)d_ws;
  _Float16* WT     = H + 12582912;   // 4 x 1048576 (W^T fp16)
  _Float16* qkv16  = H + 16777216;   // 3 x 4194304 ([B,H,S,Hd] q,k,v)
  _Float16* aout16 = H + 29360128;   // 4194304 ([B,S,D] attention out)
  float* out = (float*)d_out;

  cvt_w4<<<dim3(4, 256, 4), 256, 0, stream>>>(Wq, Wk, Wv, Wo, WT);
  gemm_qkv<<<dim3(32, 8, 3), 256, 0, stream>>>(Q, K, V, WT, bq, bk, bv, qkv16);
  attn_kernel<<<dim3(512), 256, 0, stream>>>(qkv16, qkv16 + 4194304,
                                             qkv16 + 8388608, aout16);
  gemm_out_k<<<dim3(32, 16), 256, 0, stream>>>(aout16, WT + 3145728, bo, out);
}